// Round 19
// baseline (48.442 us; speedup 1.0000x reference)
//
#include <hip/hip_runtime.h>

// GCLSTM (K=1 Cheb, H0=C0=0) fused kernel for MI355X — v20 (= v17, best).
// Math: i=sig(x@Wi+bi'), t=sig/tanh forms via exp2 (prescaled), C=i*t,
//       o=sig(x@Wo+bo'+wco*C), out = (o*tanh(C)) @ fcW + fcb.
// Final form after 18 rounds: zero-LDS zero-shuffle permuted-h dataflow,
// prescaled exp2-direct gates (6 trans/elem), cvt_pk_bf16 packing,
// 4-chunk weight bursts + input-only asm pins, zero-init accumulators
// (bias post-MFMA), 1-wave WGs, (64,3). 47.89us, absmax 7.8e-3.
// v19's extra overlaps (x/weight co-issue, fc hoist) NaN'd — reverted.

typedef __attribute__((ext_vector_type(8))) short short8;
typedef __attribute__((ext_vector_type(4))) float f32x4;

#define N_ROWS 200000
#define IN_DIM 64
#define HID 128
#define OUT_DIM 64

#define LOG2E 1.44269504f
#define TWOLOG2E 2.88539008f

// ws layout (bytes)
#define WFRAG_ELEMS (24 * 2 * 64 * 8)   // 24576 bf16 = 49152 B
#define FCFRAG_OFF  49152               // WFRAG_ELEMS*2
#define FCFRAG_ELEMS (4 * 4 * 64 * 8)   // 8192 bf16 = 16384 B
#define BIAS_OFF    65536               // floats: si[128],sc[128],so[128],swc[128] (h-permuted, prescaled), fcb[64]

__device__ __forceinline__ short f2bf(float f) {
  unsigned u = __float_as_uint(f);
  u += 0x7FFFu + ((u >> 16) & 1u);   // RNE (repack only)
  return (short)(u >> 16);
}
__device__ __forceinline__ unsigned cvt_pk_bf16(float lo, float hi) {
  unsigned r;
  asm("v_cvt_pk_bf16_f32 %0, %1, %2" : "=v"(r) : "v"(lo), "v"(hi));
  return r;
}
__device__ __forceinline__ float fexp2(float z) { return __builtin_amdgcn_exp2f(z); }
__device__ __forceinline__ float frcp(float z)  { return __builtin_amdgcn_rcpf(z); }
// permuted global hid for GEMM1 tile g (0..7), D-row d (0..15)
__device__ __forceinline__ int hperm(int g, int d) {
  return 32 * (g >> 1) + 2 * (g & 1) + 8 * (d >> 2) + 4 * ((d >> 1) & 1) + (d & 1);
}

// ---- repack: weights -> bf16 MFMA A-fragments (PRESCALED), biases fp32 ----
__global__ void repack_kernel(const float* __restrict__ W_i, const float* __restrict__ W_c,
                              const float* __restrict__ W_o, const float* __restrict__ fc_W,
                              const float* __restrict__ bg_i, const float* __restrict__ bg_c,
                              const float* __restrict__ bg_o,
                              const float* __restrict__ b_i, const float* __restrict__ b_c,
                              const float* __restrict__ b_o, const float* __restrict__ wc_o,
                              const float* __restrict__ fc_b,
                              short* __restrict__ wfrag, short* __restrict__ fcfrag,
                              float* __restrict__ bias) {
  int tid = blockIdx.x * blockDim.x + threadIdx.x;
  const int total1 = WFRAG_ELEMS;
  const int total2 = FCFRAG_ELEMS;
  for (int e = tid; e < total1 + total2 + HID + OUT_DIM; e += gridDim.x * blockDim.x) {
    if (e < total1) {
      // A-frag of GEMM1: D-row cidx of tile g, k=32s+8q+j, PERMUTED h, PRESCALED
      int j = e & 7, lane = (e >> 3) & 63, s = (e >> 9) & 1, t = e >> 10;
      int q = lane >> 4, cidx = lane & 15;
      int gate = t >> 3;                       // 0:W_i 1:W_c 2:W_o
      int g = t & 7;
      int h = hperm(g, cidx);
      int feat = 32 * s + 8 * q + j;
      const float* W = (gate == 0) ? W_i : ((gate == 1) ? W_c : W_o);
      float scale = (gate == 1) ? TWOLOG2E : -LOG2E;
      wfrag[e] = f2bf(W[feat * HID + h] * scale);
    } else if (e < total1 + total2) {
      // A-frag of GEMM2: A = fc_W^T (64x128), STANDARD hid = 32s+8q+j
      int e2 = e - total1;
      int j = e2 & 7, lane = (e2 >> 3) & 63, s = (e2 >> 9) & 3, t = e2 >> 11;
      int q = lane >> 4, cidx = lane & 15;
      int od = 16 * t + cidx;
      int hid = 32 * s + 8 * q + j;
      fcfrag[e2] = f2bf(fc_W[hid * OUT_DIM + od]);
    } else if (e < total1 + total2 + HID) {
      int p = e - total1 - total2;             // permuted storage index g*16+d
      int h = hperm(p >> 4, p & 15);
      bias[p]           = -LOG2E  * (bg_i[h] + b_i[h]);
      bias[HID + p]     = TWOLOG2E * (bg_c[h] + b_c[h]);
      bias[2 * HID + p] = -LOG2E  * (bg_o[h] + b_o[h]);
      bias[3 * HID + p] = -LOG2E  * wc_o[h];
    } else {
      int h2 = e - total1 - total2 - HID;
      bias[4 * HID + h2] = fc_b[h2];
    }
  }
}

// ---- fused main kernel: 1 wave per WG, 32 rows, burst-pipelined loads ----
__global__ __launch_bounds__(64, 3) void gclstm_fused(
    const float* __restrict__ x, const short* __restrict__ wfrag,
    const short* __restrict__ fcfrag, const float* __restrict__ bias,
    float* __restrict__ out) {
  const int lane = threadIdx.x;          // 0..63
  const int wid = blockIdx.x;            // 0..6249
  const size_t row0 = (size_t)wid * 32;
  const int q = lane >> 4, c = lane & 15;
  const short* wf = wfrag + lane * 8;
  const short* ff = fcfrag + lane * 8;

  union U { unsigned u[4]; short8 s8; };

  // x B-fragments: B = x^T; lane supplies col (row row0+16m+c), k=32sk+8q+j
  short8 bx[2][2];
#pragma unroll
  for (int m = 0; m < 2; ++m) {
    const float* xr = x + (row0 + 16 * m + c) * IN_DIM + 8 * q;
#pragma unroll
    for (int sk = 0; sk < 2; ++sk) {
      f32x4 f0 = *(const f32x4*)(xr + 32 * sk);
      f32x4 f1 = *(const f32x4*)(xr + 32 * sk + 4);
      U v;
      v.u[0] = cvt_pk_bf16(f0[0], f0[1]);
      v.u[1] = cvt_pk_bf16(f0[2], f0[3]);
      v.u[2] = cvt_pk_bf16(f1[0], f1[1]);
      v.u[3] = cvt_pk_bf16(f1[2], f1[3]);
      bx[m][sk] = v.s8;
    }
  }

  const float* Si  = bias;               // prescaled, permuted (index g*16+d)
  const float* Sc  = bias + HID;
  const float* So  = bias + 2 * HID;
  const float* Swc = bias + 3 * HID;
  const float* Fcb = bias + 4 * HID;     // standard od order

  // ---- Phase 1: 4 chunks x {12-load burst -> pin -> 2 h-tiles} ----
  unsigned hbuf[8][2][2];                // [g][m][word]
#pragma unroll
  for (int ch = 0; ch < 4; ++ch) {
    short8 w[2][3][2];                   // [gg][gate][sk] = 48 VGPR
#pragma unroll
    for (int gg = 0; gg < 2; ++gg) {
      const int g = ch * 2 + gg;
      w[gg][0][0] = *(const short8*)(wf + ((g     ) * 2 + 0) * 512);
      w[gg][0][1] = *(const short8*)(wf + ((g     ) * 2 + 1) * 512);
      w[gg][1][0] = *(const short8*)(wf + ((g +  8) * 2 + 0) * 512);
      w[gg][1][1] = *(const short8*)(wf + ((g +  8) * 2 + 1) * 512);
      w[gg][2][0] = *(const short8*)(wf + ((g + 16) * 2 + 0) * 512);
      w[gg][2][1] = *(const short8*)(wf + ((g + 16) * 2 + 1) * 512);
    }
    // materialize: all 12 loads issue before the first MFMA consumes any
    // (input-only keep-alive pins — rule #17 idiom, no mutation)
#pragma unroll
    for (int gg = 0; gg < 2; ++gg)
#pragma unroll
      for (int gt = 0; gt < 3; ++gt)
        asm volatile("" :: "v"(w[gg][gt][0]), "v"(w[gg][gt][1]));

#pragma unroll
    for (int gg = 0; gg < 2; ++gg) {
      const int g = ch * 2 + gg;
      const int p0 = g * 16 + 4 * q;
      f32x4 vbi = *(const f32x4*)(Si + p0);
      f32x4 vbc = *(const f32x4*)(Sc + p0);
      f32x4 vbo = *(const f32x4*)(So + p0);
      f32x4 vwc = *(const f32x4*)(Swc + p0);
      f32x4 acc[3][2];
#pragma unroll
      for (int m = 0; m < 2; ++m) {
        acc[0][m] = (f32x4){0.f, 0.f, 0.f, 0.f};
        acc[1][m] = (f32x4){0.f, 0.f, 0.f, 0.f};
        acc[2][m] = (f32x4){0.f, 0.f, 0.f, 0.f};
      }
#pragma unroll
      for (int sk = 0; sk < 2; ++sk)
#pragma unroll
        for (int m = 0; m < 2; ++m) {
          acc[0][m] = __builtin_amdgcn_mfma_f32_16x16x32_bf16(w[gg][0][sk], bx[m][sk], acc[0][m], 0, 0, 0);
          acc[1][m] = __builtin_amdgcn_mfma_f32_16x16x32_bf16(w[gg][1][sk], bx[m][sk], acc[1][m], 0, 0, 0);
          acc[2][m] = __builtin_amdgcn_mfma_f32_16x16x32_bf16(w[gg][2][sk], bx[m][sk], acc[2][m], 0, 0, 0);
        }
      // gates (prescaled, bias post-MFMA): ei=e^-zi, ec=e^2zc;
      // C=(ec-1)*rcp((1+ei)(1+ec)); eo=e^-(zo+wc*C); e2=e^2C;
      // H=(e2-1)*rcp((1+eo)(1+e2)).
#pragma unroll
      for (int m = 0; m < 2; ++m) {
        f32x4 z0 = acc[0][m] + vbi;
        f32x4 z1 = acc[1][m] + vbc;
        f32x4 ei, ec;
#pragma unroll
        for (int r = 0; r < 4; ++r) { ei[r] = fexp2(z0[r]); ec[r] = fexp2(z1[r]); }
        f32x4 den1 = (ei + 1.0f) * (ec + 1.0f);
        f32x4 rd1;
#pragma unroll
        for (int r = 0; r < 4; ++r) rd1[r] = frcp(den1[r]);
        f32x4 C = (ec - 1.0f) * rd1;
        f32x4 s2 = (acc[2][m] + vbo) + vwc * C;
        f32x4 t2 = C * TWOLOG2E;
        f32x4 eo, e2;
#pragma unroll
        for (int r = 0; r < 4; ++r) { eo[r] = fexp2(s2[r]); e2[r] = fexp2(t2[r]); }
        f32x4 den2 = (eo + 1.0f) * (e2 + 1.0f);
        f32x4 rd2;
#pragma unroll
        for (int r = 0; r < 4; ++r) rd2[r] = frcp(den2[r]);
        f32x4 H = (e2 - 1.0f) * rd2;
        hbuf[g][m][0] = cvt_pk_bf16(H[0], H[1]);
        hbuf[g][m][1] = cvt_pk_bf16(H[2], H[3]);
      }
    }
  }

  // ---- Phase 2: 2 halves x {8-load burst -> pin -> 2 s-blocks} ----
  f32x4 oacc[4][2];
#pragma unroll
  for (int t = 0; t < 4; ++t) {
    oacc[t][0] = (f32x4){0.f, 0.f, 0.f, 0.f};
    oacc[t][1] = (f32x4){0.f, 0.f, 0.f, 0.f};
  }
#pragma unroll
  for (int hf = 0; hf < 2; ++hf) {
    short8 af[2][4];                     // [ss][t] = 32 VGPR
#pragma unroll
    for (int ss = 0; ss < 2; ++ss)
#pragma unroll
      for (int t = 0; t < 4; ++t)
        af[ss][t] = *(const short8*)(ff + (t * 4 + (hf * 2 + ss)) * 512);
#pragma unroll
    for (int ss = 0; ss < 2; ++ss)
      asm volatile("" :: "v"(af[ss][0]), "v"(af[ss][1]), "v"(af[ss][2]), "v"(af[ss][3]));

#pragma unroll
    for (int ss = 0; ss < 2; ++ss) {
      const int s = hf * 2 + ss;
#pragma unroll
      for (int m = 0; m < 2; ++m) {
        U bu;
        bu.u[0] = hbuf[2 * s][m][0];
        bu.u[1] = hbuf[2 * s + 1][m][0];
        bu.u[2] = hbuf[2 * s][m][1];
        bu.u[3] = hbuf[2 * s + 1][m][1];
#pragma unroll
        for (int t = 0; t < 4; ++t)
          oacc[t][m] = __builtin_amdgcn_mfma_f32_16x16x32_bf16(af[ss][t], bu.s8, oacc[t][m], 0, 0, 0);
      }
    }
  }

  // ---- epilogue: add fc bias, coalesced float4 stores ----
#pragma unroll
  for (int t = 0; t < 4; ++t) {
    const int od0 = 16 * t + 4 * q;
    f32x4 fb = *(const f32x4*)(Fcb + od0);
#pragma unroll
    for (int m = 0; m < 2; ++m) {
      f32x4 v = oacc[t][m] + fb;
      *(f32x4*)(out + (row0 + 16 * m + c) * OUT_DIM + od0) = v;
    }
  }
}

extern "C" void kernel_launch(void* const* d_in, const int* in_sizes, int n_in,
                              void* d_out, int out_size, void* d_ws, size_t ws_size,
                              hipStream_t stream) {
  (void)in_sizes; (void)n_in; (void)out_size; (void)ws_size;
  const float* x    = (const float*)d_in[0];
  const float* W_i  = (const float*)d_in[3];
  const float* W_c  = (const float*)d_in[5];
  const float* W_o  = (const float*)d_in[6];
  const float* bg_i = (const float*)d_in[11];
  const float* bg_c = (const float*)d_in[13];
  const float* bg_o = (const float*)d_in[14];
  const float* wc_o = (const float*)d_in[17];
  const float* b_i  = (const float*)d_in[18];
  const float* b_c  = (const float*)d_in[20];
  const float* b_o  = (const float*)d_in[21];
  const float* fc_W = (const float*)d_in[22];
  const float* fc_b = (const float*)d_in[23];

  short* wfrag  = (short*)d_ws;
  short* fcfrag = (short*)((char*)d_ws + FCFRAG_OFF);
  float* bias   = (float*)((char*)d_ws + BIAS_OFF);

  repack_kernel<<<dim3(64), dim3(256), 0, stream>>>(
      W_i, W_c, W_o, fc_W, bg_i, bg_c, bg_o, b_i, b_c, b_o, wc_o, fc_b,
      wfrag, fcfrag, bias);

  const int nwg = N_ROWS / 32;              // 6250 single-wave WGs
  gclstm_fused<<<dim3(nwg), dim3(64), 0, stream>>>(
      x, wfrag, fcfrag, bias, (float*)d_out);
}

// Round 20
// 47.349 us; speedup vs baseline: 1.0231x; 1.0231x over previous
//
#include <hip/hip_runtime.h>

// GCLSTM (K=1 Cheb, H0=C0=0) fused kernel for MI355X — v21 (final).
// Math: i=sig(x@Wi+bi'), t=sig/tanh via exp2 (prescaled), C=i*t,
//       o=sig(x@Wo+bo'+wco*C), out = (o*tanh(C)) @ fcW + fcb.
// v21 = v17 (best, 47.9-48.4us) + (a) s_setprio(1) around MFMA clusters
//     (m191: pays for independent 1-wave staggered blocks — our structure),
//     (b) phase-2 fc loads merged into ONE 16-load burst (straight-line).

typedef __attribute__((ext_vector_type(8))) short short8;
typedef __attribute__((ext_vector_type(4))) float f32x4;

#define N_ROWS 200000
#define IN_DIM 64
#define HID 128
#define OUT_DIM 64

#define LOG2E 1.44269504f
#define TWOLOG2E 2.88539008f

// ws layout (bytes)
#define WFRAG_ELEMS (24 * 2 * 64 * 8)   // 24576 bf16 = 49152 B
#define FCFRAG_OFF  49152               // WFRAG_ELEMS*2
#define FCFRAG_ELEMS (4 * 4 * 64 * 8)   // 8192 bf16 = 16384 B
#define BIAS_OFF    65536               // floats: si[128],sc[128],so[128],swc[128] (h-permuted, prescaled), fcb[64]

__device__ __forceinline__ short f2bf(float f) {
  unsigned u = __float_as_uint(f);
  u += 0x7FFFu + ((u >> 16) & 1u);   // RNE (repack only)
  return (short)(u >> 16);
}
__device__ __forceinline__ unsigned cvt_pk_bf16(float lo, float hi) {
  unsigned r;
  asm("v_cvt_pk_bf16_f32 %0, %1, %2" : "=v"(r) : "v"(lo), "v"(hi));
  return r;
}
__device__ __forceinline__ float fexp2(float z) { return __builtin_amdgcn_exp2f(z); }
__device__ __forceinline__ float frcp(float z)  { return __builtin_amdgcn_rcpf(z); }
// permuted global hid for GEMM1 tile g (0..7), D-row d (0..15)
__device__ __forceinline__ int hperm(int g, int d) {
  return 32 * (g >> 1) + 2 * (g & 1) + 8 * (d >> 2) + 4 * ((d >> 1) & 1) + (d & 1);
}

// ---- repack: weights -> bf16 MFMA A-fragments (PRESCALED), biases fp32 ----
__global__ void repack_kernel(const float* __restrict__ W_i, const float* __restrict__ W_c,
                              const float* __restrict__ W_o, const float* __restrict__ fc_W,
                              const float* __restrict__ bg_i, const float* __restrict__ bg_c,
                              const float* __restrict__ bg_o,
                              const float* __restrict__ b_i, const float* __restrict__ b_c,
                              const float* __restrict__ b_o, const float* __restrict__ wc_o,
                              const float* __restrict__ fc_b,
                              short* __restrict__ wfrag, short* __restrict__ fcfrag,
                              float* __restrict__ bias) {
  int tid = blockIdx.x * blockDim.x + threadIdx.x;
  const int total1 = WFRAG_ELEMS;
  const int total2 = FCFRAG_ELEMS;
  for (int e = tid; e < total1 + total2 + HID + OUT_DIM; e += gridDim.x * blockDim.x) {
    if (e < total1) {
      // A-frag of GEMM1: D-row cidx of tile g, k=32s+8q+j, PERMUTED h, PRESCALED
      int j = e & 7, lane = (e >> 3) & 63, s = (e >> 9) & 1, t = e >> 10;
      int q = lane >> 4, cidx = lane & 15;
      int gate = t >> 3;                       // 0:W_i 1:W_c 2:W_o
      int g = t & 7;
      int h = hperm(g, cidx);
      int feat = 32 * s + 8 * q + j;
      const float* W = (gate == 0) ? W_i : ((gate == 1) ? W_c : W_o);
      float scale = (gate == 1) ? TWOLOG2E : -LOG2E;
      wfrag[e] = f2bf(W[feat * HID + h] * scale);
    } else if (e < total1 + total2) {
      // A-frag of GEMM2: A = fc_W^T (64x128), STANDARD hid = 32s+8q+j
      int e2 = e - total1;
      int j = e2 & 7, lane = (e2 >> 3) & 63, s = (e2 >> 9) & 3, t = e2 >> 11;
      int q = lane >> 4, cidx = lane & 15;
      int od = 16 * t + cidx;
      int hid = 32 * s + 8 * q + j;
      fcfrag[e2] = f2bf(fc_W[hid * OUT_DIM + od]);
    } else if (e < total1 + total2 + HID) {
      int p = e - total1 - total2;             // permuted storage index g*16+d
      int h = hperm(p >> 4, p & 15);
      bias[p]           = -LOG2E  * (bg_i[h] + b_i[h]);
      bias[HID + p]     = TWOLOG2E * (bg_c[h] + b_c[h]);
      bias[2 * HID + p] = -LOG2E  * (bg_o[h] + b_o[h]);
      bias[3 * HID + p] = -LOG2E  * wc_o[h];
    } else {
      int h2 = e - total1 - total2 - HID;
      bias[4 * HID + h2] = fc_b[h2];
    }
  }
}

// ---- fused main kernel: 1 wave per WG, 32 rows, burst-pipelined loads ----
__global__ __launch_bounds__(64, 3) void gclstm_fused(
    const float* __restrict__ x, const short* __restrict__ wfrag,
    const short* __restrict__ fcfrag, const float* __restrict__ bias,
    float* __restrict__ out) {
  const int lane = threadIdx.x;          // 0..63
  const int wid = blockIdx.x;            // 0..6249
  const size_t row0 = (size_t)wid * 32;
  const int q = lane >> 4, c = lane & 15;
  const short* wf = wfrag + lane * 8;
  const short* ff = fcfrag + lane * 8;

  union U { unsigned u[4]; short8 s8; };

  // x B-fragments: B = x^T; lane supplies col (row row0+16m+c), k=32sk+8q+j
  short8 bx[2][2];
#pragma unroll
  for (int m = 0; m < 2; ++m) {
    const float* xr = x + (row0 + 16 * m + c) * IN_DIM + 8 * q;
#pragma unroll
    for (int sk = 0; sk < 2; ++sk) {
      f32x4 f0 = *(const f32x4*)(xr + 32 * sk);
      f32x4 f1 = *(const f32x4*)(xr + 32 * sk + 4);
      U v;
      v.u[0] = cvt_pk_bf16(f0[0], f0[1]);
      v.u[1] = cvt_pk_bf16(f0[2], f0[3]);
      v.u[2] = cvt_pk_bf16(f1[0], f1[1]);
      v.u[3] = cvt_pk_bf16(f1[2], f1[3]);
      bx[m][sk] = v.s8;
    }
  }

  const float* Si  = bias;               // prescaled, permuted (index g*16+d)
  const float* Sc  = bias + HID;
  const float* So  = bias + 2 * HID;
  const float* Swc = bias + 3 * HID;
  const float* Fcb = bias + 4 * HID;     // standard od order

  // ---- Phase 1: 4 chunks x {12-load burst -> pin -> 2 h-tiles} ----
  unsigned hbuf[8][2][2];                // [g][m][word]
#pragma unroll
  for (int ch = 0; ch < 4; ++ch) {
    short8 w[2][3][2];                   // [gg][gate][sk] = 48 VGPR
#pragma unroll
    for (int gg = 0; gg < 2; ++gg) {
      const int g = ch * 2 + gg;
      w[gg][0][0] = *(const short8*)(wf + ((g     ) * 2 + 0) * 512);
      w[gg][0][1] = *(const short8*)(wf + ((g     ) * 2 + 1) * 512);
      w[gg][1][0] = *(const short8*)(wf + ((g +  8) * 2 + 0) * 512);
      w[gg][1][1] = *(const short8*)(wf + ((g +  8) * 2 + 1) * 512);
      w[gg][2][0] = *(const short8*)(wf + ((g + 16) * 2 + 0) * 512);
      w[gg][2][1] = *(const short8*)(wf + ((g + 16) * 2 + 1) * 512);
    }
    // materialize: all 12 loads issue before the first MFMA consumes any
#pragma unroll
    for (int gg = 0; gg < 2; ++gg)
#pragma unroll
      for (int gt = 0; gt < 3; ++gt)
        asm volatile("" :: "v"(w[gg][gt][0]), "v"(w[gg][gt][1]));

#pragma unroll
    for (int gg = 0; gg < 2; ++gg) {
      const int g = ch * 2 + gg;
      const int p0 = g * 16 + 4 * q;
      f32x4 vbi = *(const f32x4*)(Si + p0);
      f32x4 vbc = *(const f32x4*)(Sc + p0);
      f32x4 vbo = *(const f32x4*)(So + p0);
      f32x4 vwc = *(const f32x4*)(Swc + p0);
      f32x4 acc[3][2];
#pragma unroll
      for (int m = 0; m < 2; ++m) {
        acc[0][m] = (f32x4){0.f, 0.f, 0.f, 0.f};
        acc[1][m] = (f32x4){0.f, 0.f, 0.f, 0.f};
        acc[2][m] = (f32x4){0.f, 0.f, 0.f, 0.f};
      }
      __builtin_amdgcn_s_setprio(1);
#pragma unroll
      for (int sk = 0; sk < 2; ++sk)
#pragma unroll
        for (int m = 0; m < 2; ++m) {
          acc[0][m] = __builtin_amdgcn_mfma_f32_16x16x32_bf16(w[gg][0][sk], bx[m][sk], acc[0][m], 0, 0, 0);
          acc[1][m] = __builtin_amdgcn_mfma_f32_16x16x32_bf16(w[gg][1][sk], bx[m][sk], acc[1][m], 0, 0, 0);
          acc[2][m] = __builtin_amdgcn_mfma_f32_16x16x32_bf16(w[gg][2][sk], bx[m][sk], acc[2][m], 0, 0, 0);
        }
      __builtin_amdgcn_s_setprio(0);
      // gates (prescaled, bias post-MFMA): ei=e^-zi, ec=e^2zc;
      // C=(ec-1)*rcp((1+ei)(1+ec)); eo=e^-(zo+wc*C); e2=e^2C;
      // H=(e2-1)*rcp((1+eo)(1+e2)).
#pragma unroll
      for (int m = 0; m < 2; ++m) {
        f32x4 z0 = acc[0][m] + vbi;
        f32x4 z1 = acc[1][m] + vbc;
        f32x4 ei, ec;
#pragma unroll
        for (int r = 0; r < 4; ++r) { ei[r] = fexp2(z0[r]); ec[r] = fexp2(z1[r]); }
        f32x4 den1 = (ei + 1.0f) * (ec + 1.0f);
        f32x4 rd1;
#pragma unroll
        for (int r = 0; r < 4; ++r) rd1[r] = frcp(den1[r]);
        f32x4 C = (ec - 1.0f) * rd1;
        f32x4 s2 = (acc[2][m] + vbo) + vwc * C;
        f32x4 t2 = C * TWOLOG2E;
        f32x4 eo, e2;
#pragma unroll
        for (int r = 0; r < 4; ++r) { eo[r] = fexp2(s2[r]); e2[r] = fexp2(t2[r]); }
        f32x4 den2 = (eo + 1.0f) * (e2 + 1.0f);
        f32x4 rd2;
#pragma unroll
        for (int r = 0; r < 4; ++r) rd2[r] = frcp(den2[r]);
        f32x4 H = (e2 - 1.0f) * rd2;
        hbuf[g][m][0] = cvt_pk_bf16(H[0], H[1]);
        hbuf[g][m][1] = cvt_pk_bf16(H[2], H[3]);
      }
    }
  }

  // ---- Phase 2: ONE 16-load burst -> pin -> 4 s-blocks ----
  f32x4 oacc[4][2];
#pragma unroll
  for (int t = 0; t < 4; ++t) {
    oacc[t][0] = (f32x4){0.f, 0.f, 0.f, 0.f};
    oacc[t][1] = (f32x4){0.f, 0.f, 0.f, 0.f};
  }
  {
    short8 af[4][4];                     // [s][t] = 64 VGPR
#pragma unroll
    for (int s = 0; s < 4; ++s)
#pragma unroll
      for (int t = 0; t < 4; ++t)
        af[s][t] = *(const short8*)(ff + (t * 4 + s) * 512);
#pragma unroll
    for (int s = 0; s < 4; ++s)
      asm volatile("" :: "v"(af[s][0]), "v"(af[s][1]), "v"(af[s][2]), "v"(af[s][3]));

    __builtin_amdgcn_s_setprio(1);
#pragma unroll
    for (int s = 0; s < 4; ++s) {
#pragma unroll
      for (int m = 0; m < 2; ++m) {
        U bu;
        bu.u[0] = hbuf[2 * s][m][0];
        bu.u[1] = hbuf[2 * s + 1][m][0];
        bu.u[2] = hbuf[2 * s][m][1];
        bu.u[3] = hbuf[2 * s + 1][m][1];
#pragma unroll
        for (int t = 0; t < 4; ++t)
          oacc[t][m] = __builtin_amdgcn_mfma_f32_16x16x32_bf16(af[s][t], bu.s8, oacc[t][m], 0, 0, 0);
      }
    }
    __builtin_amdgcn_s_setprio(0);
  }

  // ---- epilogue: add fc bias, coalesced float4 stores ----
#pragma unroll
  for (int t = 0; t < 4; ++t) {
    const int od0 = 16 * t + 4 * q;
    f32x4 fb = *(const f32x4*)(Fcb + od0);
#pragma unroll
    for (int m = 0; m < 2; ++m) {
      f32x4 v = oacc[t][m] + fb;
      *(f32x4*)(out + (row0 + 16 * m + c) * OUT_DIM + od0) = v;
    }
  }
}

extern "C" void kernel_launch(void* const* d_in, const int* in_sizes, int n_in,
                              void* d_out, int out_size, void* d_ws, size_t ws_size,
                              hipStream_t stream) {
  (void)in_sizes; (void)n_in; (void)out_size; (void)ws_size;
  const float* x    = (const float*)d_in[0];
  const float* W_i  = (const float*)d_in[3];
  const float* W_c  = (const float*)d_in[5];
  const float* W_o  = (const float*)d_in[6];
  const float* bg_i = (const float*)d_in[11];
  const float* bg_c = (const float*)d_in[13];
  const float* bg_o = (const float*)d_in[14];
  const float* wc_o = (const float*)d_in[17];
  const float* b_i  = (const float*)d_in[18];
  const float* b_c  = (const float*)d_in[20];
  const float* b_o  = (const float*)d_in[21];
  const float* fc_W = (const float*)d_in[22];
  const float* fc_b = (const float*)d_in[23];

  short* wfrag  = (short*)d_ws;
  short* fcfrag = (short*)((char*)d_ws + FCFRAG_OFF);
  float* bias   = (float*)((char*)d_ws + BIAS_OFF);

  repack_kernel<<<dim3(64), dim3(256), 0, stream>>>(
      W_i, W_c, W_o, fc_W, bg_i, bg_c, bg_o, b_i, b_c, b_o, wc_o, fc_b,
      wfrag, fcfrag, bias);

  const int nwg = N_ROWS / 32;              // 6250 single-wave WGs
  gclstm_fused<<<dim3(nwg), dim3(64), 0, stream>>>(
      x, wfrag, fcfrag, bias, (float*)d_out);
}